// Round 9
// baseline (268.774 us; speedup 1.0000x reference)
//
#include <hip/hip_runtime.h>

#define NB 16
#define NC 8
#define HW (512 * 512)
#define GRP (HW / 4)          // 65536 float4-groups per (b,c) plane
#define TPB 512               // 8 waves; phase 1: wave w <-> channel w
#define BPB 64                // blocks per batch
#define NBLOCKS (BPB * NB)    // 1024 = 4 blocks/CU = 2048 thr/CU (needs VGPR<=64)
#define CHUNK (GRP / BPB)     // 1024 float4-groups per block
#define P1_ITERS (CHUNK / 64) // 16
#define P2_ITERS (CHUNK / TPB)// 2

// ws (floats): [0,1024) S[b][ci][ck]; [1024,1152) n[b][k]; [1152] ce_sum; [1153] ctr
#define N_BASE (NB * NC * NC)
#define CE_IDX (N_BASE + NB * NC)
#define CTR_IDX (CE_IDX + 1)
#define WS_FLOATS (CTR_IDX + 1)

// Two barrier-free phases, one kernel. r3-r8 lesson: >=64 accs/thread spills
// or kills occupancy; cross-channel exchange in the hot loop (LDS barriers or
// shfl chains) is latency-poison. Phase 1 keeps per-thread state at ~30 VGPR
// (S row for the wave's own channel); phase 2 re-reads the block's own chunk
// (L2/L3-hot from phase 1) for the cross-channel logsumexp. NO launch_bounds:
// every cap tried so far made the compiler spill (r3:64, r5:128, r8:36 VGPR).
__global__ void jce_main(const float* __restrict__ pred,
                         const int* __restrict__ target,
                         float* __restrict__ ws, float* __restrict__ out) {
  const int b = blockIdx.y;
  const int tid = threadIdx.x;
  const int w = tid >> 6;      // wave index == channel (phase 1)
  const int lane = tid & 63;
  const float* predb = pred + (size_t)b * NC * HW;
  const int4* tgt = (const int4*)(target + (size_t)b * HW);
  const int base = blockIdx.x * CHUNK;

  // ---- phase 1: S[w][k] and (wave 0) cnt[k]; coalesced, barrier-free ----
  const float4* planew = (const float4*)(predb + (size_t)w * HW);
  float S[NC], cnt[NC];
#pragma unroll
  for (int k = 0; k < NC; ++k) { S[k] = 0.0f; cnt[k] = 0.0f; }

  for (int i = 0; i < P1_ITERS; ++i) {
    const int g = base + i * 64 + lane;
    const int4 t4 = tgt[g];          // 8 waves read same line: L1/L2 broadcast
    const float4 p4 = planew[g];     // 1KB contiguous per wave per instr
#pragma unroll
    for (int j = 0; j < 4; ++j) {
      const int tc = (j == 0) ? t4.x : (j == 1) ? t4.y : (j == 2) ? t4.z : t4.w;
      const float pv = (j == 0) ? p4.x : (j == 1) ? p4.y : (j == 2) ? p4.z : p4.w;
#pragma unroll
      for (int k = 0; k < NC; ++k) {
        const float m = (tc == k) ? 1.0f : 0.0f;
        S[k] = fmaf(m, pv, S[k]);
        if (w == 0) cnt[k] += m;
      }
    }
  }

  // ---- phase 2: CE logsumexp over the same chunk (cache-hot), no target ----
  // NLL term comes free later as trace(S).
  float ce = 0.0f;
#pragma unroll
  for (int it = 0; it < P2_ITERS; ++it) {
    const int g = base + it * TPB + tid;
    float4 es = {0.0f, 0.0f, 0.0f, 0.0f};
#pragma unroll
    for (int c = 0; c < NC; ++c) {
      const float4 p4 = ((const float4*)(predb + (size_t)c * HW))[g];
      es.x += __expf(p4.x);
      es.y += __expf(p4.y);
      es.z += __expf(p4.z);
      es.w += __expf(p4.w);
    }
    ce += __logf(es.x) + __logf(es.y) + __logf(es.z) + __logf(es.w);
  }

  // ---- reductions: full-wave butterfly, tiny LDS, per-block atomics ----
#pragma unroll
  for (int k = 0; k < NC; ++k) {
#pragma unroll
    for (int m = 1; m <= 32; m <<= 1) S[k] += __shfl_xor(S[k], m);
  }
  if (w == 0) {
#pragma unroll
    for (int k = 0; k < NC; ++k) {
#pragma unroll
      for (int m = 1; m <= 32; m <<= 1) cnt[k] += __shfl_xor(cnt[k], m);
    }
  }
#pragma unroll
  for (int m = 1; m <= 32; m <<= 1) ce += __shfl_xor(ce, m);

  __shared__ float redS[NC][NC];   // [wave==channel][k]
  __shared__ float redC[NC];
  __shared__ float redE[NC];
  if (lane == 0) {
#pragma unroll
    for (int k = 0; k < NC; ++k) redS[w][k] = S[k];
    if (w == 0) {
#pragma unroll
      for (int k = 0; k < NC; ++k) redC[k] = cnt[k];
    }
    redE[w] = ce;
  }
  __syncthreads();
  if (tid < NC * NC) {
    atomicAdd(&ws[b * NC * NC + tid], redS[tid >> 3][tid & 7]);
  } else if (tid < NC * NC + NC) {
    atomicAdd(&ws[N_BASE + b * NC + (tid - NC * NC)], redC[tid - NC * NC]);
  } else if (tid == NC * NC + NC) {
    float v = 0.0f;
#pragma unroll
    for (int ww = 0; ww < NC; ++ww) v += redE[ww];
    atomicAdd(&ws[CE_IDX], v);
  }

  // ---- last-block-done finalize ----
  __shared__ int is_last;
  __syncthreads();
  if (tid == 0) {
    __threadfence();
    unsigned prev = atomicAdd((unsigned*)&ws[CTR_IDX], 1u);
    is_last = (prev == (unsigned)(NBLOCKS - 1)) ? 1 : 0;
  }
  __syncthreads();
  if (!is_last) return;

  // atomicAdd(p, 0.0f) reads: device-coherent across per-XCD L2s.
  float acc = 0.0f, tr = 0.0f;
  for (int idx = tid; idx < NB * NC * NC; idx += TPB) {
    const int bb = idx >> 6, ci = (idx >> 3) & 7, ck = idx & 7;
    const float Sval = atomicAdd(&ws[idx], 0.0f);
    if (ci == ck) { tr += Sval; continue; }
    const float n_ck = atomicAdd(&ws[N_BASE + bb * NC + ck], 0.0f);
    const float n_ci = atomicAdd(&ws[N_BASE + bb * NC + ci], 0.0f);
    const float Sii = atomicAdd(&ws[bb * NC * NC + ci * NC + ci], 0.0f);
    acc += logf(0.5f + 0.5f * (Sii / n_ci - Sval / n_ck));
  }
#pragma unroll
  for (int m = 1; m <= 32; m <<= 1) {
    acc += __shfl_xor(acc, m);
    tr += __shfl_xor(tr, m);
  }
  __shared__ float r2[TPB / 64][2];
  if (lane == 0) { r2[w][0] = acc; r2[w][1] = tr; }
  __syncthreads();
  if (tid == 0) {
    float a = 0.0f, t = 0.0f;
#pragma unroll
    for (int ww = 0; ww < TPB / 64; ++ww) { a += r2[ww][0]; t += r2[ww][1]; }
    const float jl = -a / (float)NB;
    const float lse = atomicAdd(&ws[CE_IDX], 0.0f);
    out[0] = jl + (lse - t) / ((float)NB * (float)HW);
  }
}

extern "C" void kernel_launch(void* const* d_in, const int* in_sizes, int n_in,
                              void* d_out, int out_size, void* d_ws, size_t ws_size,
                              hipStream_t stream) {
  const float* pred = (const float*)d_in[0];
  const int* target = (const int*)d_in[1];
  float* out = (float*)d_out;
  float* ws = (float*)d_ws;

  hipMemsetAsync(ws, 0, WS_FLOATS * sizeof(float), stream);
  dim3 grid(BPB, NB);
  jce_main<<<grid, TPB, 0, stream>>>(pred, target, ws, out);
}